// Round 3
// baseline (177.410 us; speedup 1.0000x reference)
//
#include <hip/hip_runtime.h>

// ---------------------------------------------------------------------------
// Attention forward: out = softmax((X Wq^T + bq)(X Wk^T + bk)^T / 8) (X Wv^T + bv)
// B=2, S=2048, H=1024, NH=16, HD=64.  All matmuls in bf16 MFMA, fp32 accum.
// Round 12: attn K/V staging double-buffered (2-phase prefetch): issue next
// tile's global_load_lds BEFORE computing current tile; ONE barrier per iter
// (its implicit vmcnt(0) is the only drain) -> HBM latency hides under the
// ~600-cyc compute phase instead of serializing.  s_setprio(1) around the
// compute cluster (T5, attn-measured +4-7%).  Inner loop re-phased
// QK -> V-load -> PV so K frags die before V frags live (VGPR <= 128 cap).
// Keeps Round-11 K=32 full-rate PV via permuted QK subtiles.
// ---------------------------------------------------------------------------

typedef __attribute__((ext_vector_type(8))) short bf16x8;
typedef __attribute__((ext_vector_type(4))) float f32x4;

#define L2E 1.44269504088896340736f

__device__ __forceinline__ unsigned short f2bf(float x) {  // RNE
  union { float f; unsigned int u; } a; a.f = x;
  unsigned int r = (a.u + 0x7fffu + ((a.u >> 16) & 1u)) >> 16;
  return (unsigned short)r;
}
__device__ __forceinline__ unsigned int fbits(float x) {
  union { float f; unsigned int u; } a; a.f = x; return a.u;
}

// pack 8 fp32 -> 8 bf16 (A-operand k-order) with HW packed convert if present
__device__ __forceinline__ bf16x8 pack_bf16x8(float p0, float p1, float p2, float p3,
                                              float p4, float p5, float p6, float p7) {
#if defined(__AMDGCN__) && __has_builtin(__builtin_amdgcn_cvt_pk_bf16_f32)
  typedef __attribute__((ext_vector_type(2))) __bf16 bf16x2_t;
  union { bf16x2_t h[4]; bf16x8 v; } pk;
  pk.h[0] = __builtin_amdgcn_cvt_pk_bf16_f32(p0, p1);
  pk.h[1] = __builtin_amdgcn_cvt_pk_bf16_f32(p2, p3);
  pk.h[2] = __builtin_amdgcn_cvt_pk_bf16_f32(p4, p5);
  pk.h[3] = __builtin_amdgcn_cvt_pk_bf16_f32(p6, p7);
  return pk.v;
#else
  unsigned u0 = fbits(p0) + 0x8000u, u1 = fbits(p1) + 0x8000u;
  unsigned u2 = fbits(p2) + 0x8000u, u3 = fbits(p3) + 0x8000u;
  unsigned u4 = fbits(p4) + 0x8000u, u5 = fbits(p5) + 0x8000u;
  unsigned u6 = fbits(p6) + 0x8000u, u7 = fbits(p7) + 0x8000u;
  union { unsigned u[4]; bf16x8 v; } pk;
  pk.u[0] = __builtin_amdgcn_perm(u1, u0, 0x07060302u);
  pk.u[1] = __builtin_amdgcn_perm(u3, u2, 0x07060302u);
  pk.u[2] = __builtin_amdgcn_perm(u5, u4, 0x07060302u);
  pk.u[3] = __builtin_amdgcn_perm(u7, u6, 0x07060302u);
  return pk.v;
#endif
}

__device__ __forceinline__ void gl_lds16(const unsigned short* g, unsigned short* l) {
  __builtin_amdgcn_global_load_lds(
      (const __attribute__((address_space(1))) void*)g,
      (__attribute__((address_space(3))) void*)l, 16, 0, 0);
}

// ---------------------------------------------------------------------------
// Kernel 1: fp32 -> bf16 conversion of hidden + the three weight matrices.
// ---------------------------------------------------------------------------
__global__ __launch_bounds__(256) void convert_all(
    const float* __restrict__ hidden, const float* __restrict__ Wq,
    const float* __restrict__ Wk, const float* __restrict__ Wv,
    unsigned short* __restrict__ Xb, unsigned short* __restrict__ Wqb,
    unsigned short* __restrict__ Wkb, unsigned short* __restrict__ Wvb) {
  int i = blockIdx.x * 256 + threadIdx.x;
  const float* src; unsigned short* dst; int off;
  if (i < 1048576)      { src = hidden; dst = Xb;  off = i; }
  else if (i < 1310720) { src = Wq;     dst = Wqb; off = i - 1048576; }
  else if (i < 1572864) { src = Wk;     dst = Wkb; off = i - 1310720; }
  else                  { src = Wv;     dst = Wvb; off = i - 1572864; }
  float4 v = ((const float4*)src)[off];
  ushort4 o;
  o.x = f2bf(v.x); o.y = f2bf(v.y); o.z = f2bf(v.z); o.w = f2bf(v.w);
  ((ushort4*)dst)[off] = o;
}

// ---------------------------------------------------------------------------
// Kernel 2: QKV projection GEMM.  Out[m,n] = sum_k A[m,k] * B[n,k]  (+bias)
//   z==0: A=X, B=Wq -> Qh [bh][s][d], pre-scaled L2E/8 (softmax fold)
//   z==1: A=X, B=Wk -> Kh [bh][s][d]
//   z==2: A=Wv, B=X -> Vh [bh][d][s]   (V TRANSPOSED, stores stay coalesced)
// 128x128 tile, BK=64, 256 threads, 16B-block XOR swizzle in LDS.
// 1D grid of 768; id&7 ~ XCD: each XCD owns a 1 MB X token-slab in its L2.
// (Unchanged this round: explicit dbuf on this structure is a measured null.)
// ---------------------------------------------------------------------------
__global__ __launch_bounds__(256) void qkv_gemm(
    const unsigned short* __restrict__ Xb,
    const unsigned short* __restrict__ Wqb, const unsigned short* __restrict__ Wkb,
    const unsigned short* __restrict__ Wvb,
    const float* __restrict__ bq, const float* __restrict__ bk,
    const float* __restrict__ bv,
    unsigned short* __restrict__ Qh, unsigned short* __restrict__ Kh,
    unsigned short* __restrict__ Vh) {
  const int id  = blockIdx.x;          // 0..767
  const int xcd = id & 7;
  const int j   = id >> 3;             // 0..95
  const int tok = xcd * 4 + (j & 3);   // token tile 0..31
  const int k2  = j >> 2;              // 0..23
  const int ft  = k2 & 7;              // feature tile 0..7
  const int z   = k2 >> 3;             // 0..2

  const unsigned short* Ap; const unsigned short* Bp;
  const float* bias; unsigned short* Out; int m0, n0;
  if (z == 2) {
    Ap = Wvb; Bp = Xb; bias = bv; Out = Vh;
    m0 = ft * 128; n0 = tok * 128;     // m: feature, n: token
  } else {
    Ap = Xb; Bp = (z == 0) ? Wqb : Wkb; bias = (z == 0) ? bq : bk;
    Out = (z == 0) ? Qh : Kh;
    m0 = tok * 128; n0 = ft * 128;     // m: token, n: feature
  }
  const float oscale = (z == 0) ? (0.125f * L2E) : 1.0f;

  __shared__ unsigned short As[128 * 64];  // 16 KB
  __shared__ unsigned short Bs[128 * 64];  // 16 KB

  const int tid  = threadIdx.x;
  const int lane = tid & 63;
  const int w    = tid >> 6;
  const int wm   = w >> 1, wn = w & 1;
  const int quad = lane >> 4;
  const int r    = lane & 15;

  f32x4 acc[4][4];
#pragma unroll
  for (int a = 0; a < 4; a++)
#pragma unroll
    for (int c = 0; c < 4; c++) acc[a][c] = (f32x4){0.f, 0.f, 0.f, 0.f};

  for (int k0 = 0; k0 < 1024; k0 += 64) {
    __syncthreads();
#pragma unroll
    for (int i = 0; i < 4; i++) {
      int t   = w * 4 + i;
      int blk = t * 64 + lane;
      int row = blk >> 3;
      int c   = (blk & 7) ^ (row & 7);
      gl_lds16(Ap + (size_t)(m0 + row) * 1024 + k0 + c * 8, &As[t * 512]);
      gl_lds16(Bp + (size_t)(n0 + row) * 1024 + k0 + c * 8, &Bs[t * 512]);
    }
    __syncthreads();

    bf16x8 af[4][2], bfv[4][2];
#pragma unroll
    for (int mi = 0; mi < 4; mi++)
#pragma unroll
      for (int ks = 0; ks < 2; ks++) {
        int row = wm * 64 + mi * 16 + r;
        int bc  = (ks * 4 + quad) ^ (row & 7);
        af[mi][ks] = *(const bf16x8*)&As[row * 64 + bc * 8];
      }
#pragma unroll
    for (int ni = 0; ni < 4; ni++)
#pragma unroll
      for (int ks = 0; ks < 2; ks++) {
        int row = wn * 64 + ni * 16 + r;
        int bc  = (ks * 4 + quad) ^ (row & 7);
        bfv[ni][ks] = *(const bf16x8*)&Bs[row * 64 + bc * 8];
      }
#pragma unroll
    for (int mi = 0; mi < 4; mi++)
#pragma unroll
      for (int ni = 0; ni < 4; ni++) {
        acc[mi][ni] = __builtin_amdgcn_mfma_f32_16x16x32_bf16(af[mi][0], bfv[ni][0], acc[mi][ni], 0, 0, 0);
        acc[mi][ni] = __builtin_amdgcn_mfma_f32_16x16x32_bf16(af[mi][1], bfv[ni][1], acc[mi][ni], 0, 0, 0);
      }
  }

  // epilogue: C/D row = quad*4+e, col = r
  if (z == 2) {
#pragma unroll
    for (int mi = 0; mi < 4; mi++)
#pragma unroll
      for (int e = 0; e < 4; e++) {
        int m = m0 + wm * 64 + mi * 16 + quad * 4 + e;  // feature
        float bm = bias[m];
#pragma unroll
        for (int ni = 0; ni < 4; ni++) {
          int n = n0 + wn * 64 + ni * 16 + r;            // token
          int bb = n >> 11, s = n & 2047;
          int hh = m >> 6,  d = m & 63;
          float v = acc[mi][ni][e] + bm;
          Out[((size_t)(bb * 16 + hh) * 64 + d) * 2048 + s] = f2bf(v);
        }
      }
  } else {
    float biasv[4];
#pragma unroll
    for (int ni = 0; ni < 4; ni++) biasv[ni] = bias[n0 + wn * 64 + ni * 16 + r];
#pragma unroll
    for (int mi = 0; mi < 4; mi++)
#pragma unroll
      for (int ni = 0; ni < 4; ni++)
#pragma unroll
        for (int e = 0; e < 4; e++) {
          int m = m0 + wm * 64 + mi * 16 + quad * 4 + e;  // token
          int n = n0 + wn * 64 + ni * 16 + r;             // feature
          int bb = m >> 11, s = m & 2047;
          int hh = n >> 6,  d = n & 63;
          float v = (acc[mi][ni][e] + biasv[ni]) * oscale;
          Out[((size_t)(bb * 16 + hh) * 2048 + s) * 64 + d] = f2bf(v);
        }
  }
}

// ---------------------------------------------------------------------------
// Kernel 3: flash attention, in-block split-KV x2, folded static-max softmax,
// register-resident P, all MFMAs K=32 full-rate, double-buffered staging.
// 512 threads = 8 waves: group g = waves [4g,4g+4) handles KV rows
// [g*1024, g*1024+1024) of the SAME 128-row q-tile; wave w%4 owns q rows
// [w*32, w*32+32) (2 fragment pairs -> K/V frags reused 2x).
// QK^T subtiles use PERMUTED kv rows: subtile A covers kv=8a+b, subtile B
// kv=8a+4+b (a,b in 0..3), so lane (r,quad) holds P[q=r][kv=8*quad+0..7]
// -> packs directly into the K=32 PV A-fragment (no cross-lane moves).
// K LDS swizzle: cs ^ ((row>>3)+2*(row&7)); V^T slot: (cs+5*row)&7.
// LDS: [buf][group][K|V] 8 tiles x 8 KB = 64 KB; merge buffer overlays.
// Per iter: stage(next tile, buf^1) -> compute(buf) -> ONE __syncthreads()
// (implicit vmcnt(0) drains prefetch) -> swap.  setprio(1) around compute.
// Grid 512 blocks -> 2 blocks/CU = 16 waves/CU.
// ---------------------------------------------------------------------------
__global__ __launch_bounds__(512, 4) void attn(
    const unsigned short* __restrict__ Qh, const unsigned short* __restrict__ Kh,
    const unsigned short* __restrict__ Vh, float* __restrict__ Out) {
  const int h = blockIdx.y, b = blockIdx.z;
  const int bh = b * 16 + h;
  const int q0 = blockIdx.x * 128;
  const unsigned short* Qp  = Qh + (size_t)bh * 2048 * 64;
  const unsigned short* Kp  = Kh + (size_t)bh * 2048 * 64;
  const unsigned short* VTp = Vh + (size_t)bh * 64 * 2048;   // [d][s]

  // 8 tiles of 64x64 bf16 (8 KB each): [buf][group][K|V].  64 KB total.
  // merge buffer (128*65 fp32 + 128 fp32 = 33.75 KB) overlays from base.
  __shared__ __align__(16) char SMRAW[65536];
  unsigned short* SMbase = (unsigned short*)SMRAW;

  const int tid  = threadIdx.x;       // 0..511
  const int lane = tid & 63;
  const int w8   = tid >> 6;          // 0..7
  const int half = w8 >> 2;           // KV half (group)
  const int w    = w8 & 3;            // q-subtile (32 rows)
  const int ltid = tid & 255;         // tid within group
  const int quad = lane >> 4;
  const int r    = lane & 15;

  // ---- issue first tile's staging before anything else ----
  const int kvbase = half * 1024;
  {
    unsigned short* Ksb  = SMbase + (half * 2 + 0) * 4096;   // buf 0
    unsigned short* Vtsb = SMbase + (half * 2 + 1) * 4096;
#pragma unroll
    for (int i = 0; i < 2; i++) {
      int blk = i * 256 + ltid;
      int row = blk >> 3;
      int cs  = blk & 7;
      int sk  = ((row >> 3) + 2 * (row & 7)) & 7;
      gl_lds16(Kp + (size_t)(kvbase + row) * 64 + ((cs ^ sk) * 8), &Ksb[blk * 8]);
      gl_lds16(VTp + (size_t)row * 2048 + kvbase + (((cs + 5 * row) & 7) * 8), &Vtsb[blk * 8]);
    }
  }

  // ---- Q fragments direct from global: rows q0 + w*32 + {0,16} + r ----
  const unsigned short* qbase = Qp + (size_t)(q0 + w * 32 + r) * 64 + quad * 8;
  bf16x8 aq0[2], aq1[2];
  aq0[0] = *(const bf16x8*)(qbase);
  aq1[0] = *(const bf16x8*)(qbase + 32);
  aq0[1] = *(const bf16x8*)(qbase + 16 * 64);
  aq1[1] = *(const bf16x8*)(qbase + 16 * 64 + 32);

  f32x4 lacc[2];
  lacc[0] = (f32x4){0.f, 0.f, 0.f, 0.f};
  lacc[1] = (f32x4){0.f, 0.f, 0.f, 0.f};
  f32x4 acc[2][4];
#pragma unroll
  for (int jq = 0; jq < 2; jq++)
#pragma unroll
    for (int dc = 0; dc < 4; dc++) acc[jq][dc] = (f32x4){0.f, 0.f, 0.f, 0.f};
  const f32x4 zero4 = (f32x4){0.f, 0.f, 0.f, 0.f};

  union { unsigned u[4]; bf16x8 v; } ou;
  ou.u[0] = 0x3F803F80u; ou.u[1] = 0x3F803F80u;
  ou.u[2] = 0x3F803F80u; ou.u[3] = 0x3F803F80u;
  const bf16x8 ones8 = ou.v;                    // B-frag of 1.0 bf16 (K=32)

  // permuted K rows for the two QK subtiles of each 32-kv pair:
  //   subtile A: kv_local = 8*(r>>2) + (r&3);  subtile B: +4
  const int prow = ((r >> 2) << 3) + (r & 3);

  __syncthreads();    // first tile staged (implicit vmcnt(0))

  int buf = 0;
  for (int kv0 = kvbase; kv0 < kvbase + 1024; kv0 += 64) {
    // ---- prefetch next tile into buf^1 (hidden under this tile's compute) ----
    if (kv0 + 64 < kvbase + 1024) {
      int nb = buf ^ 1;
      unsigned short* Ksb  = SMbase + ((nb * 2 + half) * 2 + 0) * 4096;
      unsigned short* Vtsb = SMbase + ((nb * 2 + half) * 2 + 1) * 4096;
      int nkv = kv0 + 64;
#pragma unroll
      for (int i = 0; i < 2; i++) {
        int blk = i * 256 + ltid;
        int row = blk >> 3;
        int cs  = blk & 7;
        int sk  = ((row >> 3) + 2 * (row & 7)) & 7;
        gl_lds16(Kp + (size_t)(nkv + row) * 64 + ((cs ^ sk) * 8), &Ksb[blk * 8]);
        gl_lds16(VTp + (size_t)row * 2048 + nkv + (((cs + 5 * row) & 7) * 8), &Vtsb[blk * 8]);
      }
    }

    const unsigned short* Ks  = SMbase + ((buf * 2 + half) * 2 + 0) * 4096;
    const unsigned short* Vts = SMbase + ((buf * 2 + half) * 2 + 1) * 4096;

    __builtin_amdgcn_s_setprio(1);
#pragma unroll
    for (int ncp = 0; ncp < 2; ncp++) {   // 32-kv pair within the 64 tile
      // ---- phase 1: K fragments (permuted rows) + QK^T + softmax ----
      int rowA = ncp * 32 + prow;          // kv rows 8a+b
      int rowB = rowA + 4;                 // kv rows 8a+4+b
      int sA = ((rowA >> 3) + 2 * (rowA & 7)) & 7;
      int sB = ((rowB >> 3) + 2 * (rowB & 7)) & 7;
      bf16x8 kA0 = *(const bf16x8*)&Ks[rowA * 64 + ((quad ^ sA) * 8)];
      bf16x8 kA1 = *(const bf16x8*)&Ks[rowA * 64 + (((4 + quad) ^ sA) * 8)];
      bf16x8 kB0 = *(const bf16x8*)&Ks[rowB * 64 + ((quad ^ sB) * 8)];
      bf16x8 kB1 = *(const bf16x8*)&Ks[rowB * 64 + (((4 + quad) ^ sB) * 8)];

      bf16x8 ap8[2];
#pragma unroll
      for (int jq = 0; jq < 2; jq++) {
        // S^T subtile A: lane holds q=r, kv = 8*quad + {0..3} (log2 domain)
        f32x4 tA  = __builtin_amdgcn_mfma_f32_16x16x32_bf16(kA1, aq1[jq], zero4, 0, 0, 0);
        f32x4 sTA = __builtin_amdgcn_mfma_f32_16x16x32_bf16(kA0, aq0[jq], tA, 0, 0, 0);
        // S^T subtile B: kv = 8*quad + {4..7}
        f32x4 tB  = __builtin_amdgcn_mfma_f32_16x16x32_bf16(kB1, aq1[jq], zero4, 0, 0, 0);
        f32x4 sTB = __builtin_amdgcn_mfma_f32_16x16x32_bf16(kB0, aq0[jq], tB, 0, 0, 0);

        float pa0 = __builtin_exp2f(sTA[0]);
        float pa1 = __builtin_exp2f(sTA[1]);
        float pa2 = __builtin_exp2f(sTA[2]);
        float pa3 = __builtin_exp2f(sTA[3]);
        float pb0 = __builtin_exp2f(sTB[0]);
        float pb1 = __builtin_exp2f(sTB[1]);
        float pb2 = __builtin_exp2f(sTB[2]);
        float pb3 = __builtin_exp2f(sTB[3]);
        // A-frag (K=32): lane (r,quad) holds P[q=r][kv = 8*quad + 0..7]
        ap8[jq] = pack_bf16x8(pa0, pa1, pa2, pa3, pb0, pb1, pb2, pb3);
      }

      // ---- phase 2: V fragments (K frags now dead -> VGPR peak stays low) ----
      bf16x8 vf[4];
#pragma unroll
      for (int dc = 0; dc < 4; dc++) {
        int vrow = dc * 16 + r;
        int slot = (4 * ncp + quad + 3 * vrow) & 7;
        vf[dc] = *(const bf16x8*)&Vts[vrow * 64 + slot * 8];
      }

      // ---- phase 3: row-sums + PV (all K=32 full-rate) ----
#pragma unroll
      for (int jq = 0; jq < 2; jq++) {
        lacc[jq] = __builtin_amdgcn_mfma_f32_16x16x32_bf16(ap8[jq], ones8, lacc[jq], 0, 0, 0);
#pragma unroll
        for (int dc = 0; dc < 4; dc++)
          acc[jq][dc] = __builtin_amdgcn_mfma_f32_16x16x32_bf16(ap8[jq], vf[dc], acc[jq][dc], 0, 0, 0);
      }
    }
    __builtin_amdgcn_s_setprio(0);

    __syncthreads();   // implicit vmcnt(0): prefetched buf^1 is now resident
    buf ^= 1;
  }

  // ---- merge: group 1 -> LDS, group 0 combines and writes ----
  // acc/lacc C-layout: row(q_local) = quad*4+e, col = r.  lacc replicated
  // across r (every column of the ones product is the same row sum).
  float* Abuf = (float*)SMRAW;                  // 128 q x 65 floats (padded)
  float* Lbuf = Abuf + 128 * 65;                // 128 floats
  if (half == 1) {
#pragma unroll
    for (int jq = 0; jq < 2; jq++)
#pragma unroll
      for (int e = 0; e < 4; e++) {
        int q = w * 32 + jq * 16 + quad * 4 + e;
#pragma unroll
        for (int dc = 0; dc < 4; dc++)
          Abuf[q * 65 + dc * 16 + r] = acc[jq][dc][e];
        if (r == 0) Lbuf[q] = lacc[jq][e];
      }
  }
  __syncthreads();
  if (half == 0) {
#pragma unroll
    for (int jq = 0; jq < 2; jq++)
#pragma unroll
      for (int e = 0; e < 4; e++) {
        int q = w * 32 + jq * 16 + quad * 4 + e;
        float l = lacc[jq][e] + Lbuf[q];        // total row sum
        float inv = 1.f / l;
        int s = q0 + q;
#pragma unroll
        for (int dc = 0; dc < 4; dc++) {
          int d = dc * 16 + r;
          float v = acc[jq][dc][e] + Abuf[q * 65 + d];
          Out[(size_t)(b * 2048 + s) * 1024 + h * 64 + d] = v * inv;
        }
      }
  }
}

// ---------------------------------------------------------------------------
// Workspace layout (bytes):
//   Qh  @ 0         8388608   [bh][s][d] bf16, pre-scaled L2E/8
//   Kh  @ 8388608   8388608   [bh][s][d] bf16
//   Vh  @ 16777216  8388608   [bh][d][s] bf16 (TRANSPOSED)
//   Xb  @ 25165824  8388608   bf16
//   Wqb @ 33554432  2097152, Wkb @ 35651584, Wvb @ 37748736
//   total 39845888 (~38 MB)
// ---------------------------------------------------------------------------
extern "C" void kernel_launch(void* const* d_in, const int* in_sizes, int n_in,
                              void* d_out, int out_size, void* d_ws, size_t ws_size,
                              hipStream_t stream) {
  const float* hidden = (const float*)d_in[0];
  const float* Wq = (const float*)d_in[1];
  const float* bq = (const float*)d_in[2];
  const float* Wk = (const float*)d_in[3];
  const float* bk = (const float*)d_in[4];
  const float* Wv = (const float*)d_in[5];
  const float* bv = (const float*)d_in[6];
  float* out = (float*)d_out;

  char* ws = (char*)d_ws;
  unsigned short* Qhp = (unsigned short*)(ws + 0);
  unsigned short* Khp = (unsigned short*)(ws + 8388608);
  unsigned short* Vhp = (unsigned short*)(ws + 16777216);
  unsigned short* Xb  = (unsigned short*)(ws + 25165824);
  unsigned short* Wqb = (unsigned short*)(ws + 33554432);
  unsigned short* Wkb = (unsigned short*)(ws + 35651584);
  unsigned short* Wvb = (unsigned short*)(ws + 37748736);

  convert_all<<<7168, 256, 0, stream>>>(hidden, Wq, Wk, Wv, Xb, Wqb, Wkb, Wvb);
  qkv_gemm<<<768, 256, 0, stream>>>(Xb, Wqb, Wkb, Wvb, bq, bk, bv,
                                    Qhp, Khp, Vhp);
  attn<<<dim3(16, 16, 2), 512, 0, stream>>>(Qhp, Khp, Vhp, out);
}

// Round 13
// 177.371 us; speedup vs baseline: 1.0002x; 1.0002x over previous
//
#include <hip/hip_runtime.h>

// ---------------------------------------------------------------------------
// Attention forward: out = softmax((X Wq^T + bq)(X Wk^T + bk)^T / 8) (X Wv^T + bv)
// B=2, S=2048, H=1024, NH=16, HD=64.  All matmuls in bf16 MFMA, fp32 accum.
// Round 22 == Round 13 resubmit (R13..R21 never ran: acquisition timeouts).
// R3 counters: VALUBusy 63% vs MfmaUtil 26%, VGPR=60 -> compiler
// rematerialized all swizzled LDS fragment addresses + staging addresses
// EVERY iteration (~100 VALU cyc/wave-iter).  Fix: precompute 16 fragment
// offsets + 4 staging pointer pairs ONCE; unroll the kv loop x2 so the buffer
// bit is a compile-time +16384-element offset (folds into ds_read offset
// immediates); staging pointers advance by constant strides.
// Keeps R11 K=32 full-rate PV + R12 dbuf prefetch/setprio.
// qkv_gemm intentionally untouched: 2-phase dbuf on this structure is a
// measured null (learn_hip m99/m100/m131-m140), and its dur is bounded <61us.
// ---------------------------------------------------------------------------

typedef __attribute__((ext_vector_type(8))) short bf16x8;
typedef __attribute__((ext_vector_type(4))) float f32x4;

#define L2E 1.44269504088896340736f

__device__ __forceinline__ unsigned short f2bf(float x) {  // RNE
  union { float f; unsigned int u; } a; a.f = x;
  unsigned int r = (a.u + 0x7fffu + ((a.u >> 16) & 1u)) >> 16;
  return (unsigned short)r;
}
__device__ __forceinline__ unsigned int fbits(float x) {
  union { float f; unsigned int u; } a; a.f = x; return a.u;
}

// pack 8 fp32 -> 8 bf16 (A-operand k-order) with HW packed convert if present
__device__ __forceinline__ bf16x8 pack_bf16x8(float p0, float p1, float p2, float p3,
                                              float p4, float p5, float p6, float p7) {
#if defined(__AMDGCN__) && __has_builtin(__builtin_amdgcn_cvt_pk_bf16_f32)
  typedef __attribute__((ext_vector_type(2))) __bf16 bf16x2_t;
  union { bf16x2_t h[4]; bf16x8 v; } pk;
  pk.h[0] = __builtin_amdgcn_cvt_pk_bf16_f32(p0, p1);
  pk.h[1] = __builtin_amdgcn_cvt_pk_bf16_f32(p2, p3);
  pk.h[2] = __builtin_amdgcn_cvt_pk_bf16_f32(p4, p5);
  pk.h[3] = __builtin_amdgcn_cvt_pk_bf16_f32(p6, p7);
  return pk.v;
#else
  unsigned u0 = fbits(p0) + 0x8000u, u1 = fbits(p1) + 0x8000u;
  unsigned u2 = fbits(p2) + 0x8000u, u3 = fbits(p3) + 0x8000u;
  unsigned u4 = fbits(p4) + 0x8000u, u5 = fbits(p5) + 0x8000u;
  unsigned u6 = fbits(p6) + 0x8000u, u7 = fbits(p7) + 0x8000u;
  union { unsigned u[4]; bf16x8 v; } pk;
  pk.u[0] = __builtin_amdgcn_perm(u1, u0, 0x07060302u);
  pk.u[1] = __builtin_amdgcn_perm(u3, u2, 0x07060302u);
  pk.u[2] = __builtin_amdgcn_perm(u5, u4, 0x07060302u);
  pk.u[3] = __builtin_amdgcn_perm(u7, u6, 0x07060302u);
  return pk.v;
#endif
}

__device__ __forceinline__ void gl_lds16(const unsigned short* g, unsigned short* l) {
  __builtin_amdgcn_global_load_lds(
      (const __attribute__((address_space(1))) void*)g,
      (__attribute__((address_space(3))) void*)l, 16, 0, 0);
}

// ---------------------------------------------------------------------------
// Kernel 1: fp32 -> bf16 conversion of hidden + the three weight matrices.
// ---------------------------------------------------------------------------
__global__ __launch_bounds__(256) void convert_all(
    const float* __restrict__ hidden, const float* __restrict__ Wq,
    const float* __restrict__ Wk, const float* __restrict__ Wv,
    unsigned short* __restrict__ Xb, unsigned short* __restrict__ Wqb,
    unsigned short* __restrict__ Wkb, unsigned short* __restrict__ Wvb) {
  int i = blockIdx.x * 256 + threadIdx.x;
  const float* src; unsigned short* dst; int off;
  if (i < 1048576)      { src = hidden; dst = Xb;  off = i; }
  else if (i < 1310720) { src = Wq;     dst = Wqb; off = i - 1048576; }
  else if (i < 1572864) { src = Wk;     dst = Wkb; off = i - 1310720; }
  else                  { src = Wv;     dst = Wvb; off = i - 1572864; }
  float4 v = ((const float4*)src)[off];
  ushort4 o;
  o.x = f2bf(v.x); o.y = f2bf(v.y); o.z = f2bf(v.z); o.w = f2bf(v.w);
  ((ushort4*)dst)[off] = o;
}

// ---------------------------------------------------------------------------
// Kernel 2: QKV projection GEMM.  Out[m,n] = sum_k A[m,k] * B[n,k]  (+bias)
//   z==0: A=X, B=Wq -> Qh [bh][s][d], pre-scaled L2E/8 (softmax fold)
//   z==1: A=X, B=Wk -> Kh [bh][s][d]
//   z==2: A=Wv, B=X -> Vh [bh][d][s]   (V TRANSPOSED, stores stay coalesced)
// 128x128 tile, BK=64, 256 threads, 16B-block XOR swizzle in LDS.
// 1D grid of 768; id&7 ~ XCD: each XCD owns a 1 MB X token-slab in its L2.
// ---------------------------------------------------------------------------
__global__ __launch_bounds__(256) void qkv_gemm(
    const unsigned short* __restrict__ Xb,
    const unsigned short* __restrict__ Wqb, const unsigned short* __restrict__ Wkb,
    const unsigned short* __restrict__ Wvb,
    const float* __restrict__ bq, const float* __restrict__ bk,
    const float* __restrict__ bv,
    unsigned short* __restrict__ Qh, unsigned short* __restrict__ Kh,
    unsigned short* __restrict__ Vh) {
  const int id  = blockIdx.x;          // 0..767
  const int xcd = id & 7;
  const int j   = id >> 3;             // 0..95
  const int tok = xcd * 4 + (j & 3);   // token tile 0..31
  const int k2  = j >> 2;              // 0..23
  const int ft  = k2 & 7;              // feature tile 0..7
  const int z   = k2 >> 3;             // 0..2

  const unsigned short* Ap; const unsigned short* Bp;
  const float* bias; unsigned short* Out; int m0, n0;
  if (z == 2) {
    Ap = Wvb; Bp = Xb; bias = bv; Out = Vh;
    m0 = ft * 128; n0 = tok * 128;     // m: feature, n: token
  } else {
    Ap = Xb; Bp = (z == 0) ? Wqb : Wkb; bias = (z == 0) ? bq : bk;
    Out = (z == 0) ? Qh : Kh;
    m0 = tok * 128; n0 = ft * 128;     // m: token, n: feature
  }
  const float oscale = (z == 0) ? (0.125f * L2E) : 1.0f;

  __shared__ unsigned short As[128 * 64];  // 16 KB
  __shared__ unsigned short Bs[128 * 64];  // 16 KB

  const int tid  = threadIdx.x;
  const int lane = tid & 63;
  const int w    = tid >> 6;
  const int wm   = w >> 1, wn = w & 1;
  const int quad = lane >> 4;
  const int r    = lane & 15;

  f32x4 acc[4][4];
#pragma unroll
  for (int a = 0; a < 4; a++)
#pragma unroll
    for (int c = 0; c < 4; c++) acc[a][c] = (f32x4){0.f, 0.f, 0.f, 0.f};

  for (int k0 = 0; k0 < 1024; k0 += 64) {
    __syncthreads();
#pragma unroll
    for (int i = 0; i < 4; i++) {
      int t   = w * 4 + i;
      int blk = t * 64 + lane;
      int row = blk >> 3;
      int c   = (blk & 7) ^ (row & 7);
      gl_lds16(Ap + (size_t)(m0 + row) * 1024 + k0 + c * 8, &As[t * 512]);
      gl_lds16(Bp + (size_t)(n0 + row) * 1024 + k0 + c * 8, &Bs[t * 512]);
    }
    __syncthreads();

    bf16x8 af[4][2], bfv[4][2];
#pragma unroll
    for (int mi = 0; mi < 4; mi++)
#pragma unroll
      for (int ks = 0; ks < 2; ks++) {
        int row = wm * 64 + mi * 16 + r;
        int bc  = (ks * 4 + quad) ^ (row & 7);
        af[mi][ks] = *(const bf16x8*)&As[row * 64 + bc * 8];
      }
#pragma unroll
    for (int ni = 0; ni < 4; ni++)
#pragma unroll
      for (int ks = 0; ks < 2; ks++) {
        int row = wn * 64 + ni * 16 + r;
        int bc  = (ks * 4 + quad) ^ (row & 7);
        bfv[ni][ks] = *(const bf16x8*)&Bs[row * 64 + bc * 8];
      }
#pragma unroll
    for (int mi = 0; mi < 4; mi++)
#pragma unroll
      for (int ni = 0; ni < 4; ni++) {
        acc[mi][ni] = __builtin_amdgcn_mfma_f32_16x16x32_bf16(af[mi][0], bfv[ni][0], acc[mi][ni], 0, 0, 0);
        acc[mi][ni] = __builtin_amdgcn_mfma_f32_16x16x32_bf16(af[mi][1], bfv[ni][1], acc[mi][ni], 0, 0, 0);
      }
  }

  // epilogue: C/D row = quad*4+e, col = r
  if (z == 2) {
#pragma unroll
    for (int mi = 0; mi < 4; mi++)
#pragma unroll
      for (int e = 0; e < 4; e++) {
        int m = m0 + wm * 64 + mi * 16 + quad * 4 + e;  // feature
        float bm = bias[m];
#pragma unroll
        for (int ni = 0; ni < 4; ni++) {
          int n = n0 + wn * 64 + ni * 16 + r;            // token
          int bb = n >> 11, s = n & 2047;
          int hh = m >> 6,  d = m & 63;
          float v = acc[mi][ni][e] + bm;
          Out[((size_t)(bb * 16 + hh) * 64 + d) * 2048 + s] = f2bf(v);
        }
      }
  } else {
    float biasv[4];
#pragma unroll
    for (int ni = 0; ni < 4; ni++) biasv[ni] = bias[n0 + wn * 64 + ni * 16 + r];
#pragma unroll
    for (int mi = 0; mi < 4; mi++)
#pragma unroll
      for (int ni = 0; ni < 4; ni++)
#pragma unroll
        for (int e = 0; e < 4; e++) {
          int m = m0 + wm * 64 + mi * 16 + quad * 4 + e;  // token
          int n = n0 + wn * 64 + ni * 16 + r;             // feature
          int bb = m >> 11, s = m & 2047;
          int hh = n >> 6,  d = n & 63;
          float v = (acc[mi][ni][e] + biasv[ni]) * oscale;
          Out[((size_t)(bb * 16 + hh) * 2048 + s) * 64 + d] = f2bf(v);
        }
  }
}

// ---------------------------------------------------------------------------
// attn tile compute: boff is a COMPILE-TIME buffer offset (0 or 16384 elems)
// at every call site, so all ds_read addresses are loop-invariant registers
// with the buffer bit folded into the offset immediate.
// ---------------------------------------------------------------------------
__device__ __forceinline__ void attn_tile(
    const unsigned short* SMbase, int boff,
    const int kfo[2][4], const int vfo[2][4],
    const bf16x8 aq0[2], const bf16x8 aq1[2],
    const bf16x8 ones8, f32x4 lacc[2], f32x4 acc[2][4]) {
  const f32x4 zero4 = (f32x4){0.f, 0.f, 0.f, 0.f};
#pragma unroll
  for (int ncp = 0; ncp < 2; ncp++) {
    bf16x8 kA0 = *(const bf16x8*)&SMbase[kfo[ncp][0] + boff];
    bf16x8 kA1 = *(const bf16x8*)&SMbase[kfo[ncp][1] + boff];
    bf16x8 kB0 = *(const bf16x8*)&SMbase[kfo[ncp][2] + boff];
    bf16x8 kB1 = *(const bf16x8*)&SMbase[kfo[ncp][3] + boff];

    bf16x8 ap8[2];
#pragma unroll
    for (int jq = 0; jq < 2; jq++) {
      // S^T subtile A: lane holds q=r, kv = 8*quad + {0..3} (log2 domain)
      f32x4 tA  = __builtin_amdgcn_mfma_f32_16x16x32_bf16(kA1, aq1[jq], zero4, 0, 0, 0);
      f32x4 sTA = __builtin_amdgcn_mfma_f32_16x16x32_bf16(kA0, aq0[jq], tA, 0, 0, 0);
      // S^T subtile B: kv = 8*quad + {4..7}
      f32x4 tB  = __builtin_amdgcn_mfma_f32_16x16x32_bf16(kB1, aq1[jq], zero4, 0, 0, 0);
      f32x4 sTB = __builtin_amdgcn_mfma_f32_16x16x32_bf16(kB0, aq0[jq], tB, 0, 0, 0);

      float pa0 = __builtin_exp2f(sTA[0]);
      float pa1 = __builtin_exp2f(sTA[1]);
      float pa2 = __builtin_exp2f(sTA[2]);
      float pa3 = __builtin_exp2f(sTA[3]);
      float pb0 = __builtin_exp2f(sTB[0]);
      float pb1 = __builtin_exp2f(sTB[1]);
      float pb2 = __builtin_exp2f(sTB[2]);
      float pb3 = __builtin_exp2f(sTB[3]);
      // A-frag (K=32): lane (r,quad) holds P[q=r][kv = 8*quad + 0..7]
      ap8[jq] = pack_bf16x8(pa0, pa1, pa2, pa3, pb0, pb1, pb2, pb3);
    }

    bf16x8 vf[4];
#pragma unroll
    for (int dc = 0; dc < 4; dc++)
      vf[dc] = *(const bf16x8*)&SMbase[vfo[ncp][dc] + boff];

#pragma unroll
    for (int jq = 0; jq < 2; jq++) {
      lacc[jq] = __builtin_amdgcn_mfma_f32_16x16x32_bf16(ap8[jq], ones8, lacc[jq], 0, 0, 0);
#pragma unroll
      for (int dc = 0; dc < 4; dc++)
        acc[jq][dc] = __builtin_amdgcn_mfma_f32_16x16x32_bf16(ap8[jq], vf[dc], acc[jq][dc], 0, 0, 0);
    }
  }
}

// ---------------------------------------------------------------------------
// Kernel 3: flash attention, in-block split-KV x2, folded static-max softmax,
// register-resident P, all MFMAs K=32 full-rate, double-buffered staging,
// fully strength-reduced addressing (kv loop unrolled x2, compile-time buf).
// 512 threads = 8 waves: group g handles KV rows [g*1024, g*1024+1024) of the
// SAME 128-row q-tile; wave w%4 owns q rows [w*32,w*32+32) (2 frag pairs).
// LDS: [buf][group][K|V] 8 tiles x 8 KB = 64 KB; merge buffer overlays.
// Grid 512 blocks -> 2 blocks/CU = 16 waves/CU.
// ---------------------------------------------------------------------------
__global__ __launch_bounds__(512, 4) void attn(
    const unsigned short* __restrict__ Qh, const unsigned short* __restrict__ Kh,
    const unsigned short* __restrict__ Vh, float* __restrict__ Out) {
  const int h = blockIdx.y, b = blockIdx.z;
  const int bh = b * 16 + h;
  const int q0 = blockIdx.x * 128;
  const unsigned short* Qp  = Qh + (size_t)bh * 2048 * 64;
  const unsigned short* Kp  = Kh + (size_t)bh * 2048 * 64;
  const unsigned short* VTp = Vh + (size_t)bh * 64 * 2048;   // [d][s]

  // 8 tiles of 64x64 bf16 (8 KB each): [buf][group][K|V].  64 KB total.
  // buf1 = buf0 + 16384 elements (32768 B, folds into ds_read offset).
  __shared__ __align__(16) char SMRAW[65536];
  unsigned short* SMbase = (unsigned short*)SMRAW;

  const int tid  = threadIdx.x;       // 0..511
  const int lane = tid & 63;
  const int w8   = tid >> 6;          // 0..7
  const int half = w8 >> 2;           // KV half (group)
  const int w    = w8 & 3;            // q-subtile (32 rows)
  const int ltid = tid & 255;         // tid within group
  const int quad = lane >> 4;
  const int r    = lane & 15;

  const int kvbase = half * 1024;
  const int gK = half * 8192;         // group K tile base (elements, buf0)
  const int gV = gK + 4096;           // group V tile base

  // ---- staging addresses: precompute once, advance by constant strides ----
  const int blk0 = ltid, blk1 = 256 + ltid;
  const int row0 = blk0 >> 3, cs0 = blk0 & 7;
  const int row1 = blk1 >> 3, cs1 = blk1 & 7;
  const int sk0 = ((row0 >> 3) + 2 * (row0 & 7)) & 7;
  const int sk1 = ((row1 >> 3) + 2 * (row1 & 7)) & 7;
  const unsigned short* gK0 = Kp + (size_t)(kvbase + row0) * 64 + ((cs0 ^ sk0) * 8);
  const unsigned short* gK1 = Kp + (size_t)(kvbase + row1) * 64 + ((cs1 ^ sk1) * 8);
  const unsigned short* gV0 = VTp + (size_t)row0 * 2048 + kvbase + (((cs0 + 5 * row0) & 7) * 8);
  const unsigned short* gV1 = VTp + (size_t)row1 * 2048 + kvbase + (((cs1 + 5 * row1) & 7) * 8);
  const int dKo0 = gK + blk0 * 8, dKo1 = gK + blk1 * 8;
  const int dVo0 = gV + blk0 * 8, dVo1 = gV + blk1 * 8;

#define STAGE(BOFF)                                        \
  do {                                                     \
    gl_lds16(gK0, &SMbase[dKo0 + (BOFF)]);                 \
    gl_lds16(gK1, &SMbase[dKo1 + (BOFF)]);                 \
    gl_lds16(gV0, &SMbase[dVo0 + (BOFF)]);                 \
    gl_lds16(gV1, &SMbase[dVo1 + (BOFF)]);                 \
    gK0 += 64 * 64; gK1 += 64 * 64; gV0 += 64; gV1 += 64;  \
  } while (0)

  // ---- issue first tile's staging before anything else ----
  STAGE(0);

  // ---- fragment LDS offsets (buf0): loop-invariant, computed ONCE ----
  const int prow = ((r >> 2) << 3) + (r & 3);  // permuted K rows (subtile A)
  int kfo[2][4], vfo[2][4];
#pragma unroll
  for (int ncp = 0; ncp < 2; ncp++) {
    const int rowA = ncp * 32 + prow;
    const int rowB = rowA + 4;
    const int sA = ((rowA >> 3) + 2 * (rowA & 7)) & 7;
    const int sB = ((rowB >> 3) + 2 * (rowB & 7)) & 7;
    kfo[ncp][0] = gK + rowA * 64 + ((quad ^ sA) * 8);
    kfo[ncp][1] = gK + rowA * 64 + (((4 + quad) ^ sA) * 8);
    kfo[ncp][2] = gK + rowB * 64 + ((quad ^ sB) * 8);
    kfo[ncp][3] = gK + rowB * 64 + (((4 + quad) ^ sB) * 8);
#pragma unroll
    for (int dc = 0; dc < 4; dc++) {
      const int vrow = dc * 16 + r;
      const int slot = (4 * ncp + quad + 3 * vrow) & 7;
      vfo[ncp][dc] = gV + vrow * 64 + slot * 8;
    }
  }

  // ---- Q fragments direct from global: rows q0 + w*32 + {0,16} + r ----
  const unsigned short* qbase = Qp + (size_t)(q0 + w * 32 + r) * 64 + quad * 8;
  bf16x8 aq0[2], aq1[2];
  aq0[0] = *(const bf16x8*)(qbase);
  aq1[0] = *(const bf16x8*)(qbase + 32);
  aq0[1] = *(const bf16x8*)(qbase + 16 * 64);
  aq1[1] = *(const bf16x8*)(qbase + 16 * 64 + 32);

  f32x4 lacc[2];
  lacc[0] = (f32x4){0.f, 0.f, 0.f, 0.f};
  lacc[1] = (f32x4){0.f, 0.f, 0.f, 0.f};
  f32x4 acc[2][4];
#pragma unroll
  for (int jq = 0; jq < 2; jq++)
#pragma unroll
    for (int dc = 0; dc < 4; dc++) acc[jq][dc] = (f32x4){0.f, 0.f, 0.f, 0.f};

  union { unsigned u[4]; bf16x8 v; } ou;
  ou.u[0] = 0x3F803F80u; ou.u[1] = 0x3F803F80u;
  ou.u[2] = 0x3F803F80u; ou.u[3] = 0x3F803F80u;
  const bf16x8 ones8 = ou.v;                    // B-frag of 1.0 bf16 (K=32)

  __syncthreads();    // first tile staged (implicit vmcnt(0))

  // ---- main loop: 8 unrolled pairs, buf is compile-time in each half ----
#pragma unroll 1
  for (int it = 0; it < 8; ++it) {
    // tile 2it in buf0; prefetch tile 2it+1 -> buf1 (hidden under compute)
    STAGE(16384);
    __builtin_amdgcn_s_setprio(1);
    attn_tile(SMbase, 0, kfo, vfo, aq0, aq1, ones8, lacc, acc);
    __builtin_amdgcn_s_setprio(0);
    __syncthreads();   // implicit vmcnt(0): buf1 resident

    // tile 2it+1 in buf1; prefetch tile 2it+2 -> buf0
    if (it < 7) STAGE(0);
    __builtin_amdgcn_s_setprio(1);
    attn_tile(SMbase, 16384, kfo, vfo, aq0, aq1, ones8, lacc, acc);
    __builtin_amdgcn_s_setprio(0);
    __syncthreads();   // implicit vmcnt(0): buf0 resident
  }
#undef STAGE

  // ---- merge: group 1 -> LDS, group 0 combines and writes ----
  // acc/lacc C-layout: row(q_local) = quad*4+e, col = r.  lacc replicated
  // across r (every column of the ones product is the same row sum).
  float* Abuf = (float*)SMRAW;                  // 128 q x 65 floats (padded)
  float* Lbuf = Abuf + 128 * 65;                // 128 floats
  if (half == 1) {
#pragma unroll
    for (int jq = 0; jq < 2; jq++)
#pragma unroll
      for (int e = 0; e < 4; e++) {
        int q = w * 32 + jq * 16 + quad * 4 + e;
#pragma unroll
        for (int dc = 0; dc < 4; dc++)
          Abuf[q * 65 + dc * 16 + r] = acc[jq][dc][e];
        if (r == 0) Lbuf[q] = lacc[jq][e];
      }
  }
  __syncthreads();
  if (half == 0) {
#pragma unroll
    for (int jq = 0; jq < 2; jq++)
#pragma unroll
      for (int e = 0; e < 4; e++) {
        int q = w * 32 + jq * 16 + quad * 4 + e;
        float l = lacc[jq][e] + Lbuf[q];        // total row sum
        float inv = 1.f / l;
        int s = q0 + q;
#pragma unroll
        for (int dc = 0; dc < 4; dc++) {
          int d = dc * 16 + r;
          float v = acc[jq][dc][e] + Abuf[q * 65 + d];
          Out[(size_t)(b * 2048 + s) * 1024 + h * 64 + d] = v * inv;
        }
      }
  }
}

// ---------------------------------------------------------------------------
// Workspace layout (bytes):
//   Qh  @ 0         8388608   [bh][s][d] bf16, pre-scaled L2E/8
//   Kh  @ 8388608   8388608   [bh][s][d] bf16
//   Vh  @ 16777216  8388608   [bh][d][s] bf16 (TRANSPOSED)
//   Xb  @ 25165824  8388608   bf16
//   Wqb @ 33554432  2097152, Wkb @ 35651584, Wvb @ 37748736
//   total 39845888 (~38 MB)
// ---------------------------------------------------------------------------
extern "C" void kernel_launch(void* const* d_in, const int* in_sizes, int n_in,
                              void* d_out, int out_size, void* d_ws, size_t ws_size,
                              hipStream_t stream) {
  const float* hidden = (const float*)d_in[0];
  const float* Wq = (const float*)d_in[1];
  const float* bq = (const float*)d_in[2];
  const float* Wk = (const float*)d_in[3];
  const float* bk = (const float*)d_in[4];
  const float* Wv = (const float*)d_in[5];
  const float* bv = (const float*)d_in[6];
  float* out = (float*)d_out;

  char* ws = (char*)d_ws;
  unsigned short* Qhp = (unsigned short*)(ws + 0);
  unsigned short* Khp = (unsigned short*)(ws + 8388608);
  unsigned short* Vhp = (unsigned short*)(ws + 16777216);
  unsigned short* Xb  = (unsigned short*)(ws + 25165824);
  unsigned short* Wqb = (unsigned short*)(ws + 33554432);
  unsigned short* Wkb = (unsigned short*)(ws + 35651584);
  unsigned short* Wvb = (unsigned short*)(ws + 37748736);

  convert_all<<<7168, 256, 0, stream>>>(hidden, Wq, Wk, Wv, Xb, Wqb, Wkb, Wvb);
  qkv_gemm<<<768, 256, 0, stream>>>(Xb, Wqb, Wkb, Wvb, bq, bk, bv,
                                    Qhp, Khp, Vhp);
  attn<<<dim3(16, 16, 2), 512, 0, stream>>>(Qhp, Khp, Vhp, out);
}